// Round 1
// baseline (346.449 us; speedup 1.0000x reference)
//
#include <hip/hip_runtime.h>

#define N 8192
#define D 512

typedef __attribute__((ext_vector_type(8))) short short8;
typedef __attribute__((ext_vector_type(4))) float f32x4;

static __device__ __forceinline__ unsigned short f2bf(float f) {
    unsigned u = __float_as_uint(f);
    unsigned r = (u + 0x7FFFu + ((u >> 16) & 1u)) >> 16;
    return (unsigned short)r;
}
static __device__ __forceinline__ float bf2f(unsigned u) {
    return __uint_as_float(u << 16);
}

// K1: row-normalize embeddings -> bf16 e[N][D]. One wave per row.
__global__ void knorm(const float* __restrict__ emb, unsigned short* __restrict__ e) {
    int row  = blockIdx.x * 4 + (threadIdx.x >> 6);
    int lane = threadIdx.x & 63;
    const float4* src = (const float4*)(emb + (size_t)row * D);
    float4 v0 = src[lane * 2];
    float4 v1 = src[lane * 2 + 1];
    float ss = v0.x*v0.x + v0.y*v0.y + v0.z*v0.z + v0.w*v0.w
             + v1.x*v1.x + v1.y*v1.y + v1.z*v1.z + v1.w*v1.w;
#pragma unroll
    for (int off = 1; off < 64; off <<= 1) ss += __shfl_xor(ss, off, 64);
    float inv = 1.0f / fmaxf(sqrtf(ss), 1e-12f);
    unsigned short h0 = f2bf(v0.x * inv), h1 = f2bf(v0.y * inv);
    unsigned short h2 = f2bf(v0.z * inv), h3 = f2bf(v0.w * inv);
    unsigned short h4 = f2bf(v1.x * inv), h5 = f2bf(v1.y * inv);
    unsigned short h6 = f2bf(v1.z * inv), h7 = f2bf(v1.w * inv);
    uint4 pk;
    pk.x = (unsigned)h0 | ((unsigned)h1 << 16);
    pk.y = (unsigned)h2 | ((unsigned)h3 << 16);
    pk.z = (unsigned)h4 | ((unsigned)h5 << 16);
    pk.w = (unsigned)h6 | ((unsigned)h7 << 16);
    ((uint4*)(e + (size_t)row * D))[lane] = pk;
}

// K2: pack thetas -> float4 (x,y,z,|t|^2); zero-init per-row accumulators + d2max.
__global__ void kpack(const float* __restrict__ th, float4* __restrict__ th4,
                      float* __restrict__ srow, unsigned* __restrict__ jminrow,
                      unsigned* __restrict__ negrow, unsigned* __restrict__ d2mb) {
    int i = blockIdx.x * 256 + threadIdx.x;
    if (i < N) {
        float x = th[3 * i], y = th[3 * i + 1], z = th[3 * i + 2];
        float4 v; v.x = x; v.y = y; v.z = z; v.w = x * x + y * y + z * z;
        th4[i] = v;
        srow[i] = 0.0f;
        jminrow[i] = 0xFFFFFFFFu;
        negrow[i] = 0u;
    }
    if (i == 0) *d2mb = 0u;
}

// K3: global max of squared pairwise theta distance (atomicMax on float bits).
__global__ void kd2max(const float4* __restrict__ th4, unsigned* __restrict__ d2mb) {
    int T = blockIdx.x * 256 + threadIdx.x;   // 512 blocks * 256
    int i = T >> 4;                           // 16 threads per row
    float4 ti = th4[i];
    float m = 0.0f;
#pragma unroll 4
    for (int j = (T & 15); j < N; j += 16) {
        float4 tj = th4[j];
        float dot = ti.x * tj.x + ti.y * tj.y + ti.z * tj.z;
        float d2 = ti.w + tj.w - 2.0f * dot;
        m = fmaxf(m, d2);
    }
#pragma unroll
    for (int off = 1; off < 64; off <<= 1) m = fmaxf(m, __shfl_xor(m, off, 64));
    __shared__ float red[4];
    int lane = threadIdx.x & 63, w = threadIdx.x >> 6;
    if (lane == 0) red[w] = m;
    __syncthreads();
    if (threadIdx.x == 0) {
        m = fmaxf(fmaxf(red[0], red[1]), fmaxf(red[2], red[3]));
        atomicMax(d2mb, __float_as_uint(m));
    }
}

// K4: fused GEMM (e @ e^T via bf16 MFMA) + masked exp-sum + first-positive-j + any-neg.
// Grid: 256 blocks (128 row-blocks x 2 column halves), 512 threads = 8 waves (2 Mw x 4 Nw),
// wave tile 32x32 (acc[2][2] of 16x16x32 MFMA), block col-tile 128 wide, K=512.
__global__ __launch_bounds__(512) void kmain(
    const unsigned short* __restrict__ e, const float4* __restrict__ th4,
    const unsigned* __restrict__ d2mb, float* __restrict__ srow,
    unsigned* __restrict__ jminrow, unsigned* __restrict__ negrow) {
    const int tid  = threadIdx.x;
    const int lane = tid & 63;
    const int wid  = tid >> 6;   // 0..7
    const int wr   = wid >> 2;   // 0..1
    const int wc   = wid & 3;    // 0..3
    const int rowblock = (int)blockIdx.x >> 1;
    const int colhalf  = (int)blockIdx.x & 1;
    const int r0 = rowblock * 64;

    // mask thresholds in squared-distance domain
    const float dmax = sqrtf(__uint_as_float(*d2mb)) + 1e-8f;
    const float pth = 0.15f * dmax, p2 = pth * pth;
    const float nth = 0.35f * dmax, n2 = nth * nth;

    // per-lane output-row geometry: i(mt,rr) = rbase + mt*16 + rr
    const int rbase = r0 + wr * 32 + ((lane >> 4) << 2);
    float4 thi[2][4];
#pragma unroll
    for (int mt = 0; mt < 2; mt++)
#pragma unroll
        for (int rr = 0; rr < 4; rr++) thi[mt][rr] = th4[rbase + mt * 16 + rr];

    float    s[2][4];
    unsigned jm[2][4];
    unsigned ng[2][4];
#pragma unroll
    for (int mt = 0; mt < 2; mt++)
#pragma unroll
        for (int rr = 0; rr < 4; rr++) { s[mt][rr] = 0.0f; jm[mt][rr] = 0xFFFFFFFFu; ng[mt][rr] = 0u; }

    // A fragment base: row = r0 + wr*32 + (lane&15), k-offset = (lane>>4)*8
    const unsigned short* Abase = e + (size_t)(r0 + wr * 32 + (lane & 15)) * D + ((lane >> 4) << 3);

    const int t0 = colhalf * 32, t1 = t0 + 32;
    for (int t = t0; t < t1; ++t) {
        const int jb = t * 128 + wc * 32;
        const unsigned short* Bbase = e + (size_t)(jb + (lane & 15)) * D + ((lane >> 4) << 3);

        f32x4 acc00 = {0.f,0.f,0.f,0.f}, acc01 = {0.f,0.f,0.f,0.f};
        f32x4 acc10 = {0.f,0.f,0.f,0.f}, acc11 = {0.f,0.f,0.f,0.f};
#pragma unroll
        for (int k0 = 0; k0 < D; k0 += 32) {
            short8 a0 = *(const short8*)(Abase + k0);
            short8 a1 = *(const short8*)(Abase + 16 * D + k0);
            short8 b0 = *(const short8*)(Bbase + k0);
            short8 b1 = *(const short8*)(Bbase + 16 * D + k0);
            acc00 = __builtin_amdgcn_mfma_f32_16x16x32_bf16(a0, b0, acc00, 0, 0, 0);
            acc01 = __builtin_amdgcn_mfma_f32_16x16x32_bf16(a0, b1, acc01, 0, 0, 0);
            acc10 = __builtin_amdgcn_mfma_f32_16x16x32_bf16(a1, b0, acc10, 0, 0, 0);
            acc11 = __builtin_amdgcn_mfma_f32_16x16x32_bf16(a1, b1, acc11, 0, 0, 0);
        }

        // epilogue: mask + exp-sum + jmin + anyneg for this 64x128 tile (this wave: 32x32)
        const int jc = jb + (lane & 15);
        const float4 thj0 = th4[jc];
        const float4 thj1 = th4[jc + 16];
#pragma unroll
        for (int mt = 0; mt < 2; mt++) {
#pragma unroll
            for (int nt = 0; nt < 2; nt++) {
                const f32x4 a = (mt == 0) ? (nt == 0 ? acc00 : acc01) : (nt == 0 ? acc10 : acc11);
                const float4 tj = nt == 0 ? thj0 : thj1;
                const int j = jc + nt * 16;
#pragma unroll
                for (int rr = 0; rr < 4; rr++) {
                    const int i = rbase + mt * 16 + rr;
                    const float4 ti = thi[mt][rr];
                    float dot = ti.x * tj.x + ti.y * tj.y + ti.z * tj.z;
                    float d2 = fmaf(-2.0f, dot, ti.w + tj.w);
                    bool pos = (d2 < p2) && (j != i);
                    bool neg = (d2 > n2);
                    float sim = fminf(fmaxf(a[rr] * 10.0f, -30.0f), 30.0f);
                    float c = (pos || neg) ? __expf(sim - 30.0f) : 0.0f;
                    s[mt][rr] += c;
                    if (neg) ng[mt][rr] = 1u;
                    jm[mt][rr] = min(jm[mt][rr], pos ? (unsigned)j : 0xFFFFFFFFu);
                }
            }
        }
    }

    // reduce across the 16 lanes holding each row's columns
    __shared__ float    lds_s[4][64];
    __shared__ unsigned lds_j[4][64];
    __shared__ unsigned lds_n[4][64];
#pragma unroll
    for (int mt = 0; mt < 2; mt++) {
#pragma unroll
        for (int rr = 0; rr < 4; rr++) {
            float sv = s[mt][rr];
            unsigned jv = jm[mt][rr];
            unsigned nv = ng[mt][rr];
#pragma unroll
            for (int off = 1; off < 16; off <<= 1) {
                sv += __shfl_xor(sv, off, 64);
                jv = min(jv, (unsigned)__shfl_xor((int)jv, off, 64));
                nv |= (unsigned)__shfl_xor((int)nv, off, 64);
            }
            if ((lane & 15) == 0) {
                int rl = wr * 32 + mt * 16 + ((lane >> 4) << 2) + rr;
                lds_s[wc][rl] = sv;
                lds_j[wc][rl] = jv;
                lds_n[wc][rl] = nv;
            }
        }
    }
    __syncthreads();
    if (tid < 64) {
        float sv = lds_s[0][tid] + lds_s[1][tid] + lds_s[2][tid] + lds_s[3][tid];
        unsigned jv = min(min(lds_j[0][tid], lds_j[1][tid]), min(lds_j[2][tid], lds_j[3][tid]));
        unsigned nv = lds_n[0][tid] | lds_n[1][tid] | lds_n[2][tid] | lds_n[3][tid];
        // two column-halves contribute per row: 2-operand f32 add is commutative -> deterministic
        atomicAdd(&srow[r0 + tid], sv);
        atomicMin(&jminrow[r0 + tid], jv);
        atomicOr(&negrow[r0 + tid], nv);
    }
}

// K5: per-row finalize: tgt logit = clip(10 * e_i . e_jmin); per_row = 30 + log(s) - tgt.
__global__ void krow(const unsigned short* __restrict__ e, const float* __restrict__ srow,
                     const unsigned* __restrict__ jminrow, const unsigned* __restrict__ negrow,
                     float* __restrict__ pr, float* __restrict__ vf) {
    int row  = blockIdx.x * 4 + (threadIdx.x >> 6);
    int lane = threadIdx.x & 63;
    unsigned jmv = jminrow[row];
    bool valid = (jmv != 0xFFFFFFFFu) && (negrow[row] != 0u);
    float p = 0.0f;
    if (valid) {
        const uint4* a = (const uint4*)(e + (size_t)row * D);
        const uint4* b = (const uint4*)(e + (size_t)jmv * D);
        uint4 va = a[lane], vb = b[lane];
        float dot = 0.0f;
        dot += bf2f(va.x & 0xFFFFu) * bf2f(vb.x & 0xFFFFu);
        dot += bf2f(va.x >> 16)     * bf2f(vb.x >> 16);
        dot += bf2f(va.y & 0xFFFFu) * bf2f(vb.y & 0xFFFFu);
        dot += bf2f(va.y >> 16)     * bf2f(vb.y >> 16);
        dot += bf2f(va.z & 0xFFFFu) * bf2f(vb.z & 0xFFFFu);
        dot += bf2f(va.z >> 16)     * bf2f(vb.z >> 16);
        dot += bf2f(va.w & 0xFFFFu) * bf2f(vb.w & 0xFFFFu);
        dot += bf2f(va.w >> 16)     * bf2f(vb.w >> 16);
#pragma unroll
        for (int off = 1; off < 64; off <<= 1) dot += __shfl_xor(dot, off, 64);
        float sim = fminf(fmaxf(dot * 10.0f, -30.0f), 30.0f);
        p = 30.0f + logf(srow[row]) - sim;
    }
    if (lane == 0) { pr[row] = p; vf[row] = valid ? 1.0f : 0.0f; }
}

// K6: deterministic fixed-tree reduction -> scalar loss.
__global__ void kfinal(const float* __restrict__ pr, const float* __restrict__ vf,
                       float* __restrict__ out) {
    __shared__ float ls[1024];
    __shared__ float lc[1024];
    int t = threadIdx.x;
    float sv = 0.0f, cv = 0.0f;
#pragma unroll
    for (int k = 0; k < 8; k++) { sv += pr[t * 8 + k]; cv += vf[t * 8 + k]; }
    ls[t] = sv; lc[t] = cv;
    __syncthreads();
    for (int off = 512; off > 0; off >>= 1) {
        if (t < off) { ls[t] += ls[t + off]; lc[t] += lc[t + off]; }
        __syncthreads();
    }
    if (t == 0) out[0] = (lc[0] > 0.0f) ? (ls[0] / lc[0]) : 0.0f;
}

extern "C" void kernel_launch(void* const* d_in, const int* in_sizes, int n_in,
                              void* d_out, int out_size, void* d_ws, size_t ws_size,
                              hipStream_t stream) {
    const float* emb = (const float*)d_in[0];
    const float* th  = (const float*)d_in[1];
    float* out = (float*)d_out;
    char* ws = (char*)d_ws;

    unsigned short* e    = (unsigned short*)(ws);                 // 8 MB bf16 [N][D]
    float4*   th4        = (float4*)(ws + 8388608);               // 128 KB
    float*    srow       = (float*)(ws + 8519680);                // 32 KB
    unsigned* jminr      = (unsigned*)(ws + 8552448);             // 32 KB
    unsigned* negr       = (unsigned*)(ws + 8585216);             // 32 KB
    float*    pr         = (float*)(ws + 8617984);                // 32 KB
    float*    vf         = (float*)(ws + 8650752);                // 32 KB
    unsigned* d2mb       = (unsigned*)(ws + 8683520);             // 4 B

    knorm<<<N / 4, 256, 0, stream>>>(emb, e);
    kpack<<<N / 256, 256, 0, stream>>>(th, th4, srow, jminr, negr, d2mb);
    kd2max<<<512, 256, 0, stream>>>(th4, d2mb);
    kmain<<<256, 512, 0, stream>>>(e, th4, d2mb, srow, jminr, negr);
    krow<<<N / 4, 256, 0, stream>>>(e, srow, jminr, negr, pr, vf);
    kfinal<<<1, 1024, 0, stream>>>(pr, vf, out);
}

// Round 2
// 256.537 us; speedup vs baseline: 1.3505x; 1.3505x over previous
//
#include <hip/hip_runtime.h>

#define N 8192
#define D 512

typedef __attribute__((ext_vector_type(8))) short short8;
typedef __attribute__((ext_vector_type(4))) float f32x4;

typedef const __attribute__((address_space(1))) unsigned int* gas_t;
typedef __attribute__((address_space(3))) unsigned int* las_t;

static __device__ __forceinline__ unsigned short f2bf(float f) {
    unsigned u = __float_as_uint(f);
    unsigned r = (u + 0x7FFFu + ((u >> 16) & 1u)) >> 16;
    return (unsigned short)r;
}
static __device__ __forceinline__ float bf2f(unsigned u) {
    return __uint_as_float(u << 16);
}
static __device__ __forceinline__ void gl_lds16(const unsigned short* g, char* l) {
    __builtin_amdgcn_global_load_lds((gas_t)g, (las_t)l, 16, 0, 0);
}

// K1: row-normalize embeddings -> bf16 e[N][D]. One wave per row.
__global__ void knorm(const float* __restrict__ emb, unsigned short* __restrict__ e) {
    int row  = blockIdx.x * 4 + (threadIdx.x >> 6);
    int lane = threadIdx.x & 63;
    const float4* src = (const float4*)(emb + (size_t)row * D);
    float4 v0 = src[lane * 2];
    float4 v1 = src[lane * 2 + 1];
    float ss = v0.x*v0.x + v0.y*v0.y + v0.z*v0.z + v0.w*v0.w
             + v1.x*v1.x + v1.y*v1.y + v1.z*v1.z + v1.w*v1.w;
#pragma unroll
    for (int off = 1; off < 64; off <<= 1) ss += __shfl_xor(ss, off, 64);
    float inv = 1.0f / fmaxf(sqrtf(ss), 1e-12f);
    unsigned short h0 = f2bf(v0.x * inv), h1 = f2bf(v0.y * inv);
    unsigned short h2 = f2bf(v0.z * inv), h3 = f2bf(v0.w * inv);
    unsigned short h4 = f2bf(v1.x * inv), h5 = f2bf(v1.y * inv);
    unsigned short h6 = f2bf(v1.z * inv), h7 = f2bf(v1.w * inv);
    uint4 pk;
    pk.x = (unsigned)h0 | ((unsigned)h1 << 16);
    pk.y = (unsigned)h2 | ((unsigned)h3 << 16);
    pk.z = (unsigned)h4 | ((unsigned)h5 << 16);
    pk.w = (unsigned)h6 | ((unsigned)h7 << 16);
    ((uint4*)(e + (size_t)row * D))[lane] = pk;
}

// K2: pack thetas -> float4 (x,y,z,|t|^2); zero-init per-row accumulators + d2max.
__global__ void kpack(const float* __restrict__ th, float4* __restrict__ th4,
                      float* __restrict__ srow, unsigned* __restrict__ jminrow,
                      unsigned* __restrict__ negrow, unsigned* __restrict__ d2mb) {
    int i = blockIdx.x * 256 + threadIdx.x;
    if (i < N) {
        float x = th[3 * i], y = th[3 * i + 1], z = th[3 * i + 2];
        float4 v; v.x = x; v.y = y; v.z = z; v.w = x * x + y * y + z * z;
        th4[i] = v;
        srow[i] = 0.0f;
        jminrow[i] = 0xFFFFFFFFu;
        negrow[i] = 0u;
    }
    if (i == 0) *d2mb = 0u;
}

// K3: global max of squared pairwise theta distance (atomicMax on float bits).
__global__ void kd2max(const float4* __restrict__ th4, unsigned* __restrict__ d2mb) {
    int T = blockIdx.x * 256 + threadIdx.x;   // 512 blocks * 256
    int i = T >> 4;                           // 16 threads per row
    float4 ti = th4[i];
    float m = 0.0f;
#pragma unroll 4
    for (int j = (T & 15); j < N; j += 16) {
        float4 tj = th4[j];
        float dot = ti.x * tj.x + ti.y * tj.y + ti.z * tj.z;
        float d2 = ti.w + tj.w - 2.0f * dot;
        m = fmaxf(m, d2);
    }
#pragma unroll
    for (int off = 1; off < 64; off <<= 1) m = fmaxf(m, __shfl_xor(m, off, 64));
    __shared__ float red[4];
    int lane = threadIdx.x & 63, w = threadIdx.x >> 6;
    if (lane == 0) red[w] = m;
    __syncthreads();
    if (threadIdx.x == 0) {
        m = fmaxf(fmaxf(red[0], red[1]), fmaxf(red[2], red[3]));
        atomicMax(d2mb, __float_as_uint(m));
    }
}

// K4: m97-structure fused GEMM: 128x128 tile/block, BK=64, global_load_lds staging
// with XOR-swizzled source (rule #21), 4 waves (2Mx2N), acc 4x4 of 16x16x32 bf16 MFMA.
// Fused epilogue: mask + exp-sum + first-positive-j + any-neg, once per block.
__global__ __launch_bounds__(256) void kmain(
    const unsigned short* __restrict__ e, const float4* __restrict__ th4,
    const unsigned* __restrict__ d2mb, float* __restrict__ srow,
    unsigned* __restrict__ jminrow, unsigned* __restrict__ negrow) {
    __shared__ __align__(16) char sA[16384];   // A tile 128 x 64 bf16 (swizzled storage)
    __shared__ __align__(16) char sB[16384];   // B tile 128 x 64 bf16

    const int tid  = threadIdx.x;
    const int lane = tid & 63;
    const int w    = tid >> 6;        // 0..3
    const int wr   = w >> 1;          // 0..1  (M)
    const int wc   = w & 1;           // 0..1  (N)

    // XCD-aware swizzle: 4096 blocks, 8 XCDs, 512 blocks/chunk (4096 % 8 == 0)
    const int bid = (int)blockIdx.x;
    const int sb  = (bid & 7) * 512 + (bid >> 3);
    const int rb  = sb >> 6, cb = sb & 63;
    const int r0  = rb * 128, c0 = cb * 128;

    // staging geometry: chunk c covers rows 8c..8c+7 of the tile; lane writes LDS
    // linearly at chunk*1024 + lane*16; global source column pre-swizzled so that
    // LDS[row][kb] holds global (row, kb ^ ((row&7)<<4)).
    const int l8 = lane >> 3, l7 = lane & 7;
    const int srcoff = ((l7 ^ l8) << 3);     // element offset within the 64-elem K-slab
    const unsigned short* pA[4];
    const unsigned short* pB[4];
    char* dA[4];
    char* dB[4];
#pragma unroll
    for (int cc = 0; cc < 4; cc++) {
        const int c = w * 4 + cc;
        pA[cc] = e + (size_t)(r0 + 8 * c + l8) * D + srcoff;
        pB[cc] = e + (size_t)(c0 + 8 * c + l8) * D + srcoff;
        dA[cc] = sA + c * 1024;
        dB[cc] = sB + c * 1024;
    }

    const int fr = lane & 15;   // fragment row/col within 16-tile
    const int fq = lane >> 4;   // 0..3

    f32x4 acc[4][4];
#pragma unroll
    for (int mt = 0; mt < 4; mt++)
#pragma unroll
        for (int nt = 0; nt < 4; nt++) acc[mt][nt] = (f32x4){0.f, 0.f, 0.f, 0.f};

    for (int kt = 0; kt < 8; ++kt) {
        const int k0 = kt * 64;
        __syncthreads();
#pragma unroll
        for (int cc = 0; cc < 4; cc++) {
            gl_lds16(pA[cc] + k0, dA[cc]);
            gl_lds16(pB[cc] + k0, dB[cc]);
        }
        __syncthreads();
#pragma unroll
        for (int ks = 0; ks < 2; ++ks) {
            const int kb = ((ks << 6) | (fq << 4)) ^ (l7 << 4);  // swizzled k-byte
            short8 a[4], b[4];
#pragma unroll
            for (int mt = 0; mt < 4; mt++)
                a[mt] = *(const short8*)(sA + (wr * 64 + mt * 16 + fr) * 128 + kb);
#pragma unroll
            for (int nt = 0; nt < 4; nt++)
                b[nt] = *(const short8*)(sB + (wc * 64 + nt * 16 + fr) * 128 + kb);
#pragma unroll
            for (int mt = 0; mt < 4; mt++)
#pragma unroll
                for (int nt = 0; nt < 4; nt++)
                    acc[mt][nt] = __builtin_amdgcn_mfma_f32_16x16x32_bf16(
                        a[mt], b[nt], acc[mt][nt], 0, 0, 0);
        }
    }
    __syncthreads();   // LDS about to be reused for the reduction

    // mask thresholds in squared-distance domain
    const float dmax = sqrtf(__uint_as_float(*d2mb)) + 1e-8f;
    const float p2 = 0.0225f * dmax * dmax;   // (0.15*dmax)^2
    const float n2 = 0.1225f * dmax * dmax;   // (0.35*dmax)^2

    const int j0 = c0 + wc * 64 + fr;
    float4 thj[4];
#pragma unroll
    for (int nt = 0; nt < 4; nt++) thj[nt] = th4[j0 + nt * 16];

    float*    lds_s = (float*)sA;              // [2][128]
    unsigned* lds_j = (unsigned*)(sA + 1024);
    unsigned* lds_n = (unsigned*)(sA + 2048);

    const int i0 = r0 + wr * 64 + fq * 4;
#pragma unroll
    for (int mt = 0; mt < 4; mt++) {
#pragma unroll
        for (int rr = 0; rr < 4; rr++) {
            const int i = i0 + mt * 16 + rr;
            const float4 ti = th4[i];
            float sv = 0.0f; unsigned jv = 0xFFFFFFFFu, nv = 0u;
#pragma unroll
            for (int nt = 0; nt < 4; nt++) {
                const int j = j0 + nt * 16;
                const float4 tj = thj[nt];
                float dot = ti.x * tj.x + ti.y * tj.y + ti.z * tj.z;
                float d2 = fmaf(-2.0f, dot, ti.w + tj.w);
                bool pos = (d2 < p2) && (j != i);
                bool neg = (d2 > n2);
                float sim = fminf(fmaxf(acc[mt][nt][rr] * 10.0f, -30.0f), 30.0f);
                sv += (pos || neg) ? __expf(sim - 30.0f) : 0.0f;
                if (neg) nv = 1u;
                if (pos) jv = min(jv, (unsigned)j);
            }
#pragma unroll
            for (int off = 1; off < 16; off <<= 1) {
                sv += __shfl_xor(sv, off, 64);
                jv = min(jv, (unsigned)__shfl_xor((int)jv, off, 64));
                nv |= (unsigned)__shfl_xor((int)nv, off, 64);
            }
            if (fr == 0) {
                const int rl = wr * 64 + mt * 16 + fq * 4 + rr;
                lds_s[wc * 128 + rl] = sv;
                lds_j[wc * 128 + rl] = jv;
                lds_n[wc * 128 + rl] = nv;
            }
        }
    }
    __syncthreads();
    if (tid < 128) {
        float    sv = lds_s[tid] + lds_s[128 + tid];
        unsigned jv = min(lds_j[tid], lds_j[128 + tid]);
        unsigned nv = lds_n[tid] | lds_n[128 + tid];
        atomicAdd(&srow[r0 + tid], sv);
        atomicMin(&jminrow[r0 + tid], jv);
        atomicOr(&negrow[r0 + tid], nv);
    }
}

// K5: per-row finalize: tgt logit = clip(10 * e_i . e_jmin); per_row = 30 + log(s) - tgt.
__global__ void krow(const unsigned short* __restrict__ e, const float* __restrict__ srow,
                     const unsigned* __restrict__ jminrow, const unsigned* __restrict__ negrow,
                     float* __restrict__ pr, float* __restrict__ vf) {
    int row  = blockIdx.x * 4 + (threadIdx.x >> 6);
    int lane = threadIdx.x & 63;
    unsigned jmv = jminrow[row];
    bool valid = (jmv != 0xFFFFFFFFu) && (negrow[row] != 0u);
    float p = 0.0f;
    if (valid) {
        const uint4* a = (const uint4*)(e + (size_t)row * D);
        const uint4* b = (const uint4*)(e + (size_t)jmv * D);
        uint4 va = a[lane], vb = b[lane];
        float dot = 0.0f;
        dot += bf2f(va.x & 0xFFFFu) * bf2f(vb.x & 0xFFFFu);
        dot += bf2f(va.x >> 16)     * bf2f(vb.x >> 16);
        dot += bf2f(va.y & 0xFFFFu) * bf2f(vb.y & 0xFFFFu);
        dot += bf2f(va.y >> 16)     * bf2f(vb.y >> 16);
        dot += bf2f(va.z & 0xFFFFu) * bf2f(vb.z & 0xFFFFu);
        dot += bf2f(va.z >> 16)     * bf2f(vb.z >> 16);
        dot += bf2f(va.w & 0xFFFFu) * bf2f(vb.w & 0xFFFFu);
        dot += bf2f(va.w >> 16)     * bf2f(vb.w >> 16);
#pragma unroll
        for (int off = 1; off < 64; off <<= 1) dot += __shfl_xor(dot, off, 64);
        float sim = fminf(fmaxf(dot * 10.0f, -30.0f), 30.0f);
        p = 30.0f + logf(srow[row]) - sim;
    }
    if (lane == 0) { pr[row] = p; vf[row] = valid ? 1.0f : 0.0f; }
}

// K6: deterministic fixed-tree reduction -> scalar loss.
__global__ void kfinal(const float* __restrict__ pr, const float* __restrict__ vf,
                       float* __restrict__ out) {
    __shared__ float ls[1024];
    __shared__ float lc[1024];
    int t = threadIdx.x;
    float sv = 0.0f, cv = 0.0f;
#pragma unroll
    for (int k = 0; k < 8; k++) { sv += pr[t * 8 + k]; cv += vf[t * 8 + k]; }
    ls[t] = sv; lc[t] = cv;
    __syncthreads();
    for (int off = 512; off > 0; off >>= 1) {
        if (t < off) { ls[t] += ls[t + off]; lc[t] += lc[t + off]; }
        __syncthreads();
    }
    if (t == 0) out[0] = (lc[0] > 0.0f) ? (ls[0] / lc[0]) : 0.0f;
}

extern "C" void kernel_launch(void* const* d_in, const int* in_sizes, int n_in,
                              void* d_out, int out_size, void* d_ws, size_t ws_size,
                              hipStream_t stream) {
    const float* emb = (const float*)d_in[0];
    const float* th  = (const float*)d_in[1];
    float* out = (float*)d_out;
    char* ws = (char*)d_ws;

    unsigned short* e    = (unsigned short*)(ws);                 // 8 MB bf16 [N][D]
    float4*   th4        = (float4*)(ws + 8388608);               // 128 KB
    float*    srow       = (float*)(ws + 8519680);                // 32 KB
    unsigned* jminr      = (unsigned*)(ws + 8552448);             // 32 KB
    unsigned* negr       = (unsigned*)(ws + 8585216);             // 32 KB
    float*    pr         = (float*)(ws + 8617984);                // 32 KB
    float*    vf         = (float*)(ws + 8650752);                // 32 KB
    unsigned* d2mb       = (unsigned*)(ws + 8683520);             // 4 B

    knorm<<<N / 4, 256, 0, stream>>>(emb, e);
    kpack<<<N / 256, 256, 0, stream>>>(th, th4, srow, jminr, negr, d2mb);
    kd2max<<<512, 256, 0, stream>>>(th4, d2mb);
    kmain<<<4096, 256, 0, stream>>>(e, th4, d2mb, srow, jminr, negr);
    krow<<<N / 4, 256, 0, stream>>>(e, srow, jminr, negr, pr, vf);
    kfinal<<<1, 1024, 0, stream>>>(pr, vf, out);
}

// Round 3
// 179.587 us; speedup vs baseline: 1.9291x; 1.4285x over previous
//
#include <hip/hip_runtime.h>

#define N 8192
#define D 512

typedef __attribute__((ext_vector_type(8))) short short8;
typedef __attribute__((ext_vector_type(4))) float f32x4;

typedef const __attribute__((address_space(1))) unsigned int* gas_t;
typedef __attribute__((address_space(3))) unsigned int* las_t;

static __device__ __forceinline__ unsigned short f2bf(float f) {
    unsigned u = __float_as_uint(f);
    unsigned r = (u + 0x7FFFu + ((u >> 16) & 1u)) >> 16;
    return (unsigned short)r;
}
static __device__ __forceinline__ float bf2f(unsigned u) {
    return __uint_as_float(u << 16);
}
static __device__ __forceinline__ void gl_lds16(const unsigned short* g, char* l) {
    __builtin_amdgcn_global_load_lds((gas_t)g, (las_t)l, 16, 0, 0);
}
static __device__ __forceinline__ int tri_cum(int r) { return r * (129 - r) / 2; }

// K1: row-normalize embeddings -> bf16 e[N][D]. One wave per row.
__global__ void knorm(const float* __restrict__ emb, unsigned short* __restrict__ e) {
    int row  = blockIdx.x * 4 + (threadIdx.x >> 6);
    int lane = threadIdx.x & 63;
    const float4* src = (const float4*)(emb + (size_t)row * D);
    float4 v0 = src[lane * 2];
    float4 v1 = src[lane * 2 + 1];
    float ss = v0.x*v0.x + v0.y*v0.y + v0.z*v0.z + v0.w*v0.w
             + v1.x*v1.x + v1.y*v1.y + v1.z*v1.z + v1.w*v1.w;
#pragma unroll
    for (int off = 1; off < 64; off <<= 1) ss += __shfl_xor(ss, off, 64);
    float inv = 1.0f / fmaxf(sqrtf(ss), 1e-12f);
    unsigned short h0 = f2bf(v0.x * inv), h1 = f2bf(v0.y * inv);
    unsigned short h2 = f2bf(v0.z * inv), h3 = f2bf(v0.w * inv);
    unsigned short h4 = f2bf(v1.x * inv), h5 = f2bf(v1.y * inv);
    unsigned short h6 = f2bf(v1.z * inv), h7 = f2bf(v1.w * inv);
    uint4 pk;
    pk.x = (unsigned)h0 | ((unsigned)h1 << 16);
    pk.y = (unsigned)h2 | ((unsigned)h3 << 16);
    pk.z = (unsigned)h4 | ((unsigned)h5 << 16);
    pk.w = (unsigned)h6 | ((unsigned)h7 << 16);
    ((uint4*)(e + (size_t)row * D))[lane] = pk;
}

// K2: pack thetas -> float4 (x,y,z,|t|^2); zero-init per-row accumulators + d2max.
__global__ void kpack(const float* __restrict__ th, float4* __restrict__ th4,
                      float* __restrict__ srow, unsigned* __restrict__ jminrow,
                      unsigned* __restrict__ negrow, unsigned* __restrict__ d2mb) {
    int i = blockIdx.x * 256 + threadIdx.x;
    if (i < N) {
        float x = th[3 * i], y = th[3 * i + 1], z = th[3 * i + 2];
        float4 v; v.x = x; v.y = y; v.z = z; v.w = x * x + y * y + z * z;
        th4[i] = v;
        srow[i] = 0.0f;
        jminrow[i] = 0xFFFFFFFFu;
        negrow[i] = 0u;
    }
    if (i == 0) *d2mb = 0u;
}

// K3: global max of squared pairwise theta distance, symmetric (j>i only).
// One wave per row-pair (w, 8191-w): balanced ~128 iters/wave, 4096 waves.
__global__ void kd2max(const float4* __restrict__ th4, unsigned* __restrict__ d2mb) {
    int widx = blockIdx.x * 4 + (threadIdx.x >> 6);   // 0..4095
    int lane = threadIdx.x & 63;
    float4 t1 = th4[widx];
    int i2 = N - 1 - widx;
    float4 t2 = th4[i2];
    float m = 0.0f;
#pragma unroll 2
    for (int j = widx + 1 + lane; j < N; j += 64) {
        float4 tj = th4[j];
        float dot = t1.x * tj.x + t1.y * tj.y + t1.z * tj.z;
        m = fmaxf(m, t1.w + tj.w - 2.0f * dot);
    }
#pragma unroll 2
    for (int j = i2 + 1 + lane; j < N; j += 64) {
        float4 tj = th4[j];
        float dot = t2.x * tj.x + t2.y * tj.y + t2.z * tj.z;
        m = fmaxf(m, t2.w + tj.w - 2.0f * dot);
    }
#pragma unroll
    for (int off = 1; off < 64; off <<= 1) m = fmaxf(m, __shfl_xor(m, off, 64));
    if (lane == 0) atomicMax(d2mb, __float_as_uint(m));
}

// K4: symmetric fused GEMM over the upper-triangle tile grid (2080 blocks).
// 128x128 tile/block, BK=64, global_load_lds staging with XOR-swizzled source,
// 4 waves (2Mx2N), acc 4x4 of 16x16x32 bf16 MFMA. Each off-diag tile's masked
// exp values are scattered BOTH to row-i accumulators and (transposed) row-j
// accumulators; diagonal tiles contribute row-side only.
__global__ __launch_bounds__(256) void kmain(
    const unsigned short* __restrict__ e, const float4* __restrict__ th4,
    const unsigned* __restrict__ d2mb, float* __restrict__ srow,
    unsigned* __restrict__ jminrow, unsigned* __restrict__ negrow) {
    __shared__ __align__(16) char sA[16384];   // A tile 128 x 64 bf16 (swizzled storage)
    __shared__ __align__(16) char sB[16384];   // B tile 128 x 64 bf16

    const int tid  = threadIdx.x;
    const int lane = tid & 63;
    const int w    = tid >> 6;        // 0..3
    const int wr   = w >> 1;          // 0..1  (M)
    const int wc   = w & 1;           // 0..1  (N)

    // XCD-aware bijective swizzle: 2080 blocks = 8 XCDs x 260
    const int bid = (int)blockIdx.x;
    const int swz = (bid & 7) * 260 + (bid >> 3);
    // triangle decode: rb = largest r with cum(r) <= swz, cb = rb + remainder
    int rb = (int)((129.0f - sqrtf(16641.0f - 8.0f * (float)swz)) * 0.5f);
    rb = rb < 0 ? 0 : (rb > 63 ? 63 : rb);
    while (tri_cum(rb + 1) <= swz) rb++;
    while (tri_cum(rb) > swz) rb--;
    const int cb = rb + (swz - tri_cum(rb));
    const bool isdiag = (rb == cb);
    const int r0 = rb * 128, c0 = cb * 128;

    // staging geometry: chunk c covers 8 rows; lane writes LDS linearly at
    // chunk*1024 + lane*16; global source column pre-swizzled so that
    // LDS[row][kb] holds global (row, kb ^ ((row&7)<<4)).
    const int l8 = lane >> 3, l7 = lane & 7;
    const int srcoff = ((l7 ^ l8) << 3);
    const unsigned short* pA[4];
    const unsigned short* pB[4];
    char* dA[4];
    char* dB[4];
#pragma unroll
    for (int cc = 0; cc < 4; cc++) {
        const int c = w * 4 + cc;
        pA[cc] = e + (size_t)(r0 + 8 * c + l8) * D + srcoff;
        pB[cc] = e + (size_t)(c0 + 8 * c + l8) * D + srcoff;
        dA[cc] = sA + c * 1024;
        dB[cc] = sB + c * 1024;
    }

    const int fr = lane & 15;   // fragment row/col within 16-tile
    const int fq = lane >> 4;   // 0..3

    f32x4 acc[4][4];
#pragma unroll
    for (int mt = 0; mt < 4; mt++)
#pragma unroll
        for (int nt = 0; nt < 4; nt++) acc[mt][nt] = (f32x4){0.f, 0.f, 0.f, 0.f};

    for (int kt = 0; kt < 8; ++kt) {
        const int k0 = kt * 64;
        __syncthreads();
#pragma unroll
        for (int cc = 0; cc < 4; cc++) {
            gl_lds16(pA[cc] + k0, dA[cc]);
            gl_lds16(pB[cc] + k0, dB[cc]);
        }
        __syncthreads();
#pragma unroll
        for (int ks = 0; ks < 2; ++ks) {
            const int kb = ((ks << 6) | (fq << 4)) ^ (l7 << 4);  // swizzled k-byte
            short8 a[4], b[4];
#pragma unroll
            for (int mt = 0; mt < 4; mt++)
                a[mt] = *(const short8*)(sA + (wr * 64 + mt * 16 + fr) * 128 + kb);
#pragma unroll
            for (int nt = 0; nt < 4; nt++)
                b[nt] = *(const short8*)(sB + (wc * 64 + nt * 16 + fr) * 128 + kb);
#pragma unroll
            for (int mt = 0; mt < 4; mt++)
#pragma unroll
                for (int nt = 0; nt < 4; nt++)
                    acc[mt][nt] = __builtin_amdgcn_mfma_f32_16x16x32_bf16(
                        a[mt], b[nt], acc[mt][nt], 0, 0, 0);
        }
    }
    __syncthreads();   // LDS about to be reused for the reduction

    // mask thresholds in squared-distance domain
    const float dmax = sqrtf(__uint_as_float(*d2mb)) + 1e-8f;
    const float p2 = 0.0225f * dmax * dmax;   // (0.15*dmax)^2
    const float n2 = 0.1225f * dmax * dmax;   // (0.35*dmax)^2

    const int j0 = c0 + wc * 64 + fr;
    float4 thj[4];
#pragma unroll
    for (int nt = 0; nt < 4; nt++) thj[nt] = th4[j0 + nt * 16];

    float*    lds_rs = (float*)sA;              // [2][128] row sums (by wc)
    unsigned* lds_rj = (unsigned*)(sA + 1024);
    unsigned* lds_rn = (unsigned*)(sA + 2048);
    float*    lds_cs = (float*)(sA + 3072);     // [2][128] col sums (by wr)
    unsigned* lds_cj = (unsigned*)(sA + 4096);
    unsigned* lds_cn = (unsigned*)(sA + 5120);

    // column-side accumulators (per lane: columns j0 + nt*16)
    float    csum[4]; unsigned cjm[4], cng[4];
#pragma unroll
    for (int nt = 0; nt < 4; nt++) { csum[nt] = 0.0f; cjm[nt] = 0xFFFFFFFFu; cng[nt] = 0u; }

    const int i0 = r0 + wr * 64 + fq * 4;
#pragma unroll
    for (int mt = 0; mt < 4; mt++) {
#pragma unroll
        for (int rr = 0; rr < 4; rr++) {
            const int i = i0 + mt * 16 + rr;
            const float4 ti = th4[i];
            float sv = 0.0f; unsigned jv = 0xFFFFFFFFu, nv = 0u;
#pragma unroll
            for (int nt = 0; nt < 4; nt++) {
                const int j = j0 + nt * 16;
                const float4 tj = thj[nt];
                float dot = ti.x * tj.x + ti.y * tj.y + ti.z * tj.z;
                float d2 = fmaf(-2.0f, dot, ti.w + tj.w);
                bool pos = (d2 < p2) && (j != i);
                bool neg = (d2 > n2);
                float c = (pos || neg)
                    ? __expf(fminf(fmaxf(acc[mt][nt][rr] * 10.0f, -30.0f), 30.0f) - 30.0f)
                    : 0.0f;
                sv += c;
                if (neg) nv = 1u;
                if (pos) jv = min(jv, (unsigned)j);
                if (!isdiag) {
                    csum[nt] += c;
                    if (neg) cng[nt] = 1u;
                    if (pos) cjm[nt] = min(cjm[nt], (unsigned)i);
                }
            }
            // row-side reduce across the 16 fr-lanes
#pragma unroll
            for (int off = 1; off < 16; off <<= 1) {
                sv += __shfl_xor(sv, off, 64);
                jv = min(jv, (unsigned)__shfl_xor((int)jv, off, 64));
                nv |= (unsigned)__shfl_xor((int)nv, off, 64);
            }
            if (fr == 0) {
                const int rl = wr * 64 + mt * 16 + fq * 4 + rr;
                lds_rs[wc * 128 + rl] = sv;
                lds_rj[wc * 128 + rl] = jv;
                lds_rn[wc * 128 + rl] = nv;
            }
        }
    }

    // column-side reduce across the 4 fq groups (lane^16, lane^32)
    if (!isdiag) {
#pragma unroll
        for (int nt = 0; nt < 4; nt++) {
            float sv = csum[nt]; unsigned jv = cjm[nt], nv = cng[nt];
#pragma unroll
            for (int off = 16; off < 64; off <<= 1) {
                sv += __shfl_xor(sv, off, 64);
                jv = min(jv, (unsigned)__shfl_xor((int)jv, off, 64));
                nv |= (unsigned)__shfl_xor((int)nv, off, 64);
            }
            if (fq == 0) {
                const int cl = wc * 64 + nt * 16 + fr;
                lds_cs[wr * 128 + cl] = sv;
                lds_cj[wr * 128 + cl] = jv;
                lds_cn[wr * 128 + cl] = nv;
            }
        }
    }
    __syncthreads();
    if (tid < 128) {
        float    sv = lds_rs[tid] + lds_rs[128 + tid];
        unsigned jv = min(lds_rj[tid], lds_rj[128 + tid]);
        unsigned nv = lds_rn[tid] | lds_rn[128 + tid];
        atomicAdd(&srow[r0 + tid], sv);
        atomicMin(&jminrow[r0 + tid], jv);
        atomicOr(&negrow[r0 + tid], nv);
        if (!isdiag) {
            float    cv = lds_cs[tid] + lds_cs[128 + tid];
            unsigned cj = min(lds_cj[tid], lds_cj[128 + tid]);
            unsigned cn = lds_cn[tid] | lds_cn[128 + tid];
            atomicAdd(&srow[c0 + tid], cv);
            atomicMin(&jminrow[c0 + tid], cj);
            atomicOr(&negrow[c0 + tid], cn);
        }
    }
}

// K5: per-row finalize: tgt logit = clip(10 * e_i . e_jmin); per_row = 30 + log(s) - tgt.
__global__ void krow(const unsigned short* __restrict__ e, const float* __restrict__ srow,
                     const unsigned* __restrict__ jminrow, const unsigned* __restrict__ negrow,
                     float* __restrict__ pr, float* __restrict__ vf) {
    int row  = blockIdx.x * 4 + (threadIdx.x >> 6);
    int lane = threadIdx.x & 63;
    unsigned jmv = jminrow[row];
    bool valid = (jmv != 0xFFFFFFFFu) && (negrow[row] != 0u);
    float p = 0.0f;
    if (valid) {
        const uint4* a = (const uint4*)(e + (size_t)row * D);
        const uint4* b = (const uint4*)(e + (size_t)jmv * D);
        uint4 va = a[lane], vb = b[lane];
        float dot = 0.0f;
        dot += bf2f(va.x & 0xFFFFu) * bf2f(vb.x & 0xFFFFu);
        dot += bf2f(va.x >> 16)     * bf2f(vb.x >> 16);
        dot += bf2f(va.y & 0xFFFFu) * bf2f(vb.y & 0xFFFFu);
        dot += bf2f(va.y >> 16)     * bf2f(vb.y >> 16);
        dot += bf2f(va.z & 0xFFFFu) * bf2f(vb.z & 0xFFFFu);
        dot += bf2f(va.z >> 16)     * bf2f(vb.z >> 16);
        dot += bf2f(va.w & 0xFFFFu) * bf2f(vb.w & 0xFFFFu);
        dot += bf2f(va.w >> 16)     * bf2f(vb.w >> 16);
#pragma unroll
        for (int off = 1; off < 64; off <<= 1) dot += __shfl_xor(dot, off, 64);
        float sim = fminf(fmaxf(dot * 10.0f, -30.0f), 30.0f);
        p = 30.0f + logf(srow[row]) - sim;
    }
    if (lane == 0) { pr[row] = p; vf[row] = valid ? 1.0f : 0.0f; }
}

// K6: deterministic fixed-tree reduction -> scalar loss.
__global__ void kfinal(const float* __restrict__ pr, const float* __restrict__ vf,
                       float* __restrict__ out) {
    __shared__ float ls[1024];
    __shared__ float lc[1024];
    int t = threadIdx.x;
    float sv = 0.0f, cv = 0.0f;
#pragma unroll
    for (int k = 0; k < 8; k++) { sv += pr[t * 8 + k]; cv += vf[t * 8 + k]; }
    ls[t] = sv; lc[t] = cv;
    __syncthreads();
    for (int off = 512; off > 0; off >>= 1) {
        if (t < off) { ls[t] += ls[t + off]; lc[t] += lc[t + off]; }
        __syncthreads();
    }
    if (t == 0) out[0] = (lc[0] > 0.0f) ? (ls[0] / lc[0]) : 0.0f;
}

extern "C" void kernel_launch(void* const* d_in, const int* in_sizes, int n_in,
                              void* d_out, int out_size, void* d_ws, size_t ws_size,
                              hipStream_t stream) {
    const float* emb = (const float*)d_in[0];
    const float* th  = (const float*)d_in[1];
    float* out = (float*)d_out;
    char* ws = (char*)d_ws;

    unsigned short* e    = (unsigned short*)(ws);                 // 8 MB bf16 [N][D]
    float4*   th4        = (float4*)(ws + 8388608);               // 128 KB
    float*    srow       = (float*)(ws + 8519680);                // 32 KB
    unsigned* jminr      = (unsigned*)(ws + 8552448);             // 32 KB
    unsigned* negr       = (unsigned*)(ws + 8585216);             // 32 KB
    float*    pr         = (float*)(ws + 8617984);                // 32 KB
    float*    vf         = (float*)(ws + 8650752);                // 32 KB
    unsigned* d2mb       = (unsigned*)(ws + 8683520);             // 4 B

    knorm<<<N / 4, 256, 0, stream>>>(emb, e);
    kpack<<<N / 256, 256, 0, stream>>>(th, th4, srow, jminr, negr, d2mb);
    kd2max<<<1024, 256, 0, stream>>>(th4, d2mb);
    kmain<<<2080, 256, 0, stream>>>(e, th4, d2mb, srow, jminr, negr);
    krow<<<N / 4, 256, 0, stream>>>(e, srow, jminr, negr, pr, vf);
    kfinal<<<1, 1024, 0, stream>>>(pr, vf, out);
}

// Round 4
// 134.159 us; speedup vs baseline: 2.5824x; 1.3386x over previous
//
#include <hip/hip_runtime.h>

#define N 8192
#define D 512

typedef __attribute__((ext_vector_type(8))) short short8;
typedef __attribute__((ext_vector_type(4))) float f32x4;

typedef const __attribute__((address_space(1))) unsigned int* gas_t;
typedef __attribute__((address_space(3))) unsigned int* las_t;

static __device__ __forceinline__ unsigned short f2bf(float f) {
    unsigned u = __float_as_uint(f);
    unsigned r = (u + 0x7FFFu + ((u >> 16) & 1u)) >> 16;
    return (unsigned short)r;
}
static __device__ __forceinline__ float bf2f(unsigned u) {
    return __uint_as_float(u << 16);
}
static __device__ __forceinline__ void gl_lds16(const unsigned short* g, char* l) {
    __builtin_amdgcn_global_load_lds((gas_t)g, (las_t)l, 16, 0, 0);
}
static __device__ __forceinline__ int tri_cum(int r) { return r * (129 - r) / 2; }

// K1: row-normalize embeddings -> bf16 e[N][D]; also pack thetas + init accumulators.
__global__ void knorm(const float* __restrict__ emb, unsigned short* __restrict__ e,
                      const float* __restrict__ th, float4* __restrict__ th4,
                      float* __restrict__ srow, unsigned* __restrict__ jminrow,
                      unsigned* __restrict__ negrow, unsigned* __restrict__ d2mb) {
    int row  = blockIdx.x * 4 + (threadIdx.x >> 6);
    int lane = threadIdx.x & 63;
    const float4* src = (const float4*)(emb + (size_t)row * D);
    float4 v0 = src[lane * 2];
    float4 v1 = src[lane * 2 + 1];
    float ss = v0.x*v0.x + v0.y*v0.y + v0.z*v0.z + v0.w*v0.w
             + v1.x*v1.x + v1.y*v1.y + v1.z*v1.z + v1.w*v1.w;
#pragma unroll
    for (int off = 1; off < 64; off <<= 1) ss += __shfl_xor(ss, off, 64);
    float inv = 1.0f / fmaxf(sqrtf(ss), 1e-12f);
    unsigned short h0 = f2bf(v0.x * inv), h1 = f2bf(v0.y * inv);
    unsigned short h2 = f2bf(v0.z * inv), h3 = f2bf(v0.w * inv);
    unsigned short h4 = f2bf(v1.x * inv), h5 = f2bf(v1.y * inv);
    unsigned short h6 = f2bf(v1.z * inv), h7 = f2bf(v1.w * inv);
    uint4 pk;
    pk.x = (unsigned)h0 | ((unsigned)h1 << 16);
    pk.y = (unsigned)h2 | ((unsigned)h3 << 16);
    pk.z = (unsigned)h4 | ((unsigned)h5 << 16);
    pk.w = (unsigned)h6 | ((unsigned)h7 << 16);
    ((uint4*)(e + (size_t)row * D))[lane] = pk;

    int tid = threadIdx.x;
    if (tid < 4) {
        int i = blockIdx.x * 4 + tid;
        float x = th[3 * i], y = th[3 * i + 1], z = th[3 * i + 2];
        float4 v; v.x = x; v.y = y; v.z = z; v.w = x * x + y * y + z * z;
        th4[i] = v;
        srow[i] = 0.0f;
        jminrow[i] = 0xFFFFFFFFu;
        negrow[i] = 0u;
    }
    if (blockIdx.x == 0 && tid == 0) *d2mb = 0u;
}

// K3: global max of squared pairwise theta distance, symmetric (j>i only).
// One wave per row-pair (w, 8191-w); block-level reduce -> 1 atomic per block.
__global__ void kd2max(const float4* __restrict__ th4, unsigned* __restrict__ d2mb) {
    int widx = blockIdx.x * 4 + (threadIdx.x >> 6);   // 0..4095
    int lane = threadIdx.x & 63;
    float4 t1 = th4[widx];
    int i2 = N - 1 - widx;
    float4 t2 = th4[i2];
    float m = 0.0f;
#pragma unroll 4
    for (int j = widx + 1 + lane; j < N; j += 64) {
        float4 tj = th4[j];
        float dot = t1.x * tj.x + t1.y * tj.y + t1.z * tj.z;
        m = fmaxf(m, t1.w + tj.w - 2.0f * dot);
    }
#pragma unroll 4
    for (int j = i2 + 1 + lane; j < N; j += 64) {
        float4 tj = th4[j];
        float dot = t2.x * tj.x + t2.y * tj.y + t2.z * tj.z;
        m = fmaxf(m, t2.w + tj.w - 2.0f * dot);
    }
#pragma unroll
    for (int off = 1; off < 64; off <<= 1) m = fmaxf(m, __shfl_xor(m, off, 64));
    __shared__ float red[4];
    int w = threadIdx.x >> 6;
    if (lane == 0) red[w] = m;
    __syncthreads();
    if (threadIdx.x == 0) {
        m = fmaxf(fmaxf(red[0], red[1]), fmaxf(red[2], red[3]));
        atomicMax(d2mb, __float_as_uint(m));
    }
}

// K4: symmetric fused GEMM over the upper-triangle tile grid (2080 blocks).
// 128x128 tile/block, BK=64, DOUBLE-BUFFERED global_load_lds staging (2-phase:
// issue next-tile loads before computing current; vmcnt(0)+raw barrier per step),
// XOR-swizzled source, 4 waves (2Mx2N), acc 4x4 of 16x16x32 bf16 MFMA.
// Fused epilogue scatters masked exp both row-side and (off-diag) column-side.
__global__ __launch_bounds__(256) void kmain(
    const unsigned short* __restrict__ e, const float4* __restrict__ th4,
    const unsigned* __restrict__ d2mb, float* __restrict__ srow,
    unsigned* __restrict__ jminrow, unsigned* __restrict__ negrow) {
    __shared__ __align__(16) char sA0[16384];
    __shared__ __align__(16) char sB0[16384];
    __shared__ __align__(16) char sA1[16384];
    __shared__ __align__(16) char sB1[16384];

    const int tid  = threadIdx.x;
    const int lane = tid & 63;
    const int w    = tid >> 6;        // 0..3
    const int wr   = w >> 1;          // 0..1  (M)
    const int wc   = w & 1;           // 0..1  (N)

    // XCD-aware bijective swizzle: 2080 blocks = 8 XCDs x 260
    const int bid = (int)blockIdx.x;
    const int swz = (bid & 7) * 260 + (bid >> 3);
    int rb = (int)((129.0f - sqrtf(16641.0f - 8.0f * (float)swz)) * 0.5f);
    rb = rb < 0 ? 0 : (rb > 63 ? 63 : rb);
    while (tri_cum(rb + 1) <= swz) rb++;
    while (tri_cum(rb) > swz) rb--;
    const int cb = rb + (swz - tri_cum(rb));
    const bool isdiag = (rb == cb);
    const int r0 = rb * 128, c0 = cb * 128;

    // staging geometry: chunk c covers 8 rows; lane writes LDS linearly at
    // chunk*1024 + lane*16; global source column pre-swizzled so that
    // LDS[row][kb] holds global (row, kb ^ ((row&7)<<4)).
    const int l8 = lane >> 3, l7 = lane & 7;
    const int srcoff = ((l7 ^ l8) << 3);
    const unsigned short* pA[4];
    const unsigned short* pB[4];
#pragma unroll
    for (int cc = 0; cc < 4; cc++) {
        const int c = w * 4 + cc;
        pA[cc] = e + (size_t)(r0 + 8 * c + l8) * D + srcoff;
        pB[cc] = e + (size_t)(c0 + 8 * c + l8) * D + srcoff;
    }

    const int fr = lane & 15;   // fragment row/col within 16-tile
    const int fq = lane >> 4;   // 0..3

    f32x4 acc[4][4];
#pragma unroll
    for (int mt = 0; mt < 4; mt++)
#pragma unroll
        for (int nt = 0; nt < 4; nt++) acc[mt][nt] = (f32x4){0.f, 0.f, 0.f, 0.f};

    auto stage = [&](char* dA, char* dB, int k0) {
#pragma unroll
        for (int cc = 0; cc < 4; cc++) {
            gl_lds16(pA[cc] + k0, dA + (w * 4 + cc) * 1024);
            gl_lds16(pB[cc] + k0, dB + (w * 4 + cc) * 1024);
        }
    };
    auto compute = [&](const char* cA, const char* cB) {
#pragma unroll
        for (int ks = 0; ks < 2; ++ks) {
            const int kb = ((ks << 6) | (fq << 4)) ^ (l7 << 4);  // swizzled k-byte
            short8 a[4], b[4];
#pragma unroll
            for (int mt = 0; mt < 4; mt++)
                a[mt] = *(const short8*)(cA + (wr * 64 + mt * 16 + fr) * 128 + kb);
#pragma unroll
            for (int nt = 0; nt < 4; nt++)
                b[nt] = *(const short8*)(cB + (wc * 64 + nt * 16 + fr) * 128 + kb);
#pragma unroll
            for (int mt = 0; mt < 4; mt++)
#pragma unroll
                for (int nt = 0; nt < 4; nt++)
                    acc[mt][nt] = __builtin_amdgcn_mfma_f32_16x16x32_bf16(
                        a[mt], b[nt], acc[mt][nt], 0, 0, 0);
        }
    };

    // 2-phase pipeline: STAGE(t+1) issued before compute(t); vmcnt(0)+barrier/step.
    stage(sA0, sB0, 0);
    asm volatile("s_waitcnt vmcnt(0)" ::: "memory");
    __builtin_amdgcn_s_barrier();
#pragma unroll
    for (int kt = 0; kt < 8; kt += 2) {
        stage(sA1, sB1, (kt + 1) * 64);
        compute(sA0, sB0);
        asm volatile("s_waitcnt vmcnt(0)" ::: "memory");
        __builtin_amdgcn_s_barrier();
        if (kt + 2 < 8) stage(sA0, sB0, (kt + 2) * 64);
        compute(sA1, sB1);
        asm volatile("s_waitcnt vmcnt(0)" ::: "memory");
        __builtin_amdgcn_s_barrier();
    }

    // mask thresholds in squared-distance domain
    const float dmax = sqrtf(__uint_as_float(*d2mb)) + 1e-8f;
    const float p2 = 0.0225f * dmax * dmax;   // (0.15*dmax)^2
    const float n2 = 0.1225f * dmax * dmax;   // (0.35*dmax)^2

    const int j0 = c0 + wc * 64 + fr;
    float4 thj[4];
#pragma unroll
    for (int nt = 0; nt < 4; nt++) thj[nt] = th4[j0 + nt * 16];

    float*    lds_rs = (float*)sA0;              // [2][128] row sums (by wc)
    unsigned* lds_rj = (unsigned*)(sA0 + 1024);
    unsigned* lds_rn = (unsigned*)(sA0 + 2048);
    float*    lds_cs = (float*)(sA0 + 3072);     // [2][128] col sums (by wr)
    unsigned* lds_cj = (unsigned*)(sA0 + 4096);
    unsigned* lds_cn = (unsigned*)(sA0 + 5120);

    // column-side accumulators (per lane: columns j0 + nt*16)
    float    csum[4]; unsigned cjm[4], cng[4];
#pragma unroll
    for (int nt = 0; nt < 4; nt++) { csum[nt] = 0.0f; cjm[nt] = 0xFFFFFFFFu; cng[nt] = 0u; }

    // |sim| = |10 * e_i.e_j| <= 10.05 (unit rows + bf16 rounding) -> clamp at +-30
    // is a provable no-op; the -30 LSE shift is dropped (sum <= 2e8, safe in f32).
    const float K_EXP = 14.4269504089f;  // 10 * log2(e); exp(10x) = 2^(x*K_EXP)

    const int i0 = r0 + wr * 64 + fq * 4;
#pragma unroll
    for (int mt = 0; mt < 4; mt++) {
#pragma unroll
        for (int rr = 0; rr < 4; rr++) {
            const int i = i0 + mt * 16 + rr;
            const float4 ti = th4[i];
            float sv = 0.0f; unsigned jv = 0xFFFFFFFFu, nv = 0u;
#pragma unroll
            for (int nt = 0; nt < 4; nt++) {
                const int j = j0 + nt * 16;
                const float4 tj = thj[nt];
                float dot = ti.x * tj.x + ti.y * tj.y + ti.z * tj.z;
                float d2 = fmaf(-2.0f, dot, ti.w + tj.w);
                bool pos = isdiag ? ((d2 < p2) && (j != i)) : (d2 < p2);
                bool neg = (d2 > n2);
                float c = (pos || neg) ? exp2f(acc[mt][nt][rr] * K_EXP) : 0.0f;
                sv += c;
                if (neg) nv = 1u;
                if (pos) jv = min(jv, (unsigned)j);
                if (!isdiag) {
                    csum[nt] += c;
                    if (neg) cng[nt] = 1u;
                    if (pos) cjm[nt] = min(cjm[nt], (unsigned)i);
                }
            }
            // row-side reduce across the 16 fr-lanes
#pragma unroll
            for (int off = 1; off < 16; off <<= 1) {
                sv += __shfl_xor(sv, off, 64);
                jv = min(jv, (unsigned)__shfl_xor((int)jv, off, 64));
                nv |= (unsigned)__shfl_xor((int)nv, off, 64);
            }
            if (fr == 0) {
                const int rl = wr * 64 + mt * 16 + fq * 4 + rr;
                lds_rs[wc * 128 + rl] = sv;
                lds_rj[wc * 128 + rl] = jv;
                lds_rn[wc * 128 + rl] = nv;
            }
        }
    }

    // column-side reduce across the 4 fq groups (lane^16, lane^32)
    if (!isdiag) {
#pragma unroll
        for (int nt = 0; nt < 4; nt++) {
            float sv = csum[nt]; unsigned jv = cjm[nt], nv = cng[nt];
#pragma unroll
            for (int off = 16; off < 64; off <<= 1) {
                sv += __shfl_xor(sv, off, 64);
                jv = min(jv, (unsigned)__shfl_xor((int)jv, off, 64));
                nv |= (unsigned)__shfl_xor((int)nv, off, 64);
            }
            if (fq == 0) {
                const int cl = wc * 64 + nt * 16 + fr;
                lds_cs[wr * 128 + cl] = sv;
                lds_cj[wr * 128 + cl] = jv;
                lds_cn[wr * 128 + cl] = nv;
            }
        }
    }
    __syncthreads();
    if (tid < 128) {
        float    sv = lds_rs[tid] + lds_rs[128 + tid];
        unsigned jv = min(lds_rj[tid], lds_rj[128 + tid]);
        unsigned nv = lds_rn[tid] | lds_rn[128 + tid];
        atomicAdd(&srow[r0 + tid], sv);
        atomicMin(&jminrow[r0 + tid], jv);
        atomicOr(&negrow[r0 + tid], nv);
        if (!isdiag) {
            float    cv = lds_cs[tid] + lds_cs[128 + tid];
            unsigned cj = min(lds_cj[tid], lds_cj[128 + tid]);
            unsigned cn = lds_cn[tid] | lds_cn[128 + tid];
            atomicAdd(&srow[c0 + tid], cv);
            atomicMin(&jminrow[c0 + tid], cj);
            atomicOr(&negrow[c0 + tid], cn);
        }
    }
}

// K5: per-row finalize: tgt logit = 10 * e_i . e_jmin; per_row = log(s) - tgt.
__global__ void krow(const unsigned short* __restrict__ e, const float* __restrict__ srow,
                     const unsigned* __restrict__ jminrow, const unsigned* __restrict__ negrow,
                     float* __restrict__ pr, float* __restrict__ vf) {
    int row  = blockIdx.x * 4 + (threadIdx.x >> 6);
    int lane = threadIdx.x & 63;
    unsigned jmv = jminrow[row];
    bool valid = (jmv != 0xFFFFFFFFu) && (negrow[row] != 0u);
    float p = 0.0f;
    if (valid) {
        const uint4* a = (const uint4*)(e + (size_t)row * D);
        const uint4* b = (const uint4*)(e + (size_t)jmv * D);
        uint4 va = a[lane], vb = b[lane];
        float dot = 0.0f;
        dot += bf2f(va.x & 0xFFFFu) * bf2f(vb.x & 0xFFFFu);
        dot += bf2f(va.x >> 16)     * bf2f(vb.x >> 16);
        dot += bf2f(va.y & 0xFFFFu) * bf2f(vb.y & 0xFFFFu);
        dot += bf2f(va.y >> 16)     * bf2f(vb.y >> 16);
        dot += bf2f(va.z & 0xFFFFu) * bf2f(vb.z & 0xFFFFu);
        dot += bf2f(va.z >> 16)     * bf2f(vb.z >> 16);
        dot += bf2f(va.w & 0xFFFFu) * bf2f(vb.w & 0xFFFFu);
        dot += bf2f(va.w >> 16)     * bf2f(vb.w >> 16);
#pragma unroll
        for (int off = 1; off < 64; off <<= 1) dot += __shfl_xor(dot, off, 64);
        p = logf(srow[row]) - dot * 10.0f;
    }
    if (lane == 0) { pr[row] = p; vf[row] = valid ? 1.0f : 0.0f; }
}

// K6: deterministic fixed-tree reduction -> scalar loss.
__global__ void kfinal(const float* __restrict__ pr, const float* __restrict__ vf,
                       float* __restrict__ out) {
    __shared__ float ls[1024];
    __shared__ float lc[1024];
    int t = threadIdx.x;
    float sv = 0.0f, cv = 0.0f;
#pragma unroll
    for (int k = 0; k < 8; k++) { sv += pr[t * 8 + k]; cv += vf[t * 8 + k]; }
    ls[t] = sv; lc[t] = cv;
    __syncthreads();
    for (int off = 512; off > 0; off >>= 1) {
        if (t < off) { ls[t] += ls[t + off]; lc[t] += lc[t + off]; }
        __syncthreads();
    }
    if (t == 0) out[0] = (lc[0] > 0.0f) ? (ls[0] / lc[0]) : 0.0f;
}

extern "C" void kernel_launch(void* const* d_in, const int* in_sizes, int n_in,
                              void* d_out, int out_size, void* d_ws, size_t ws_size,
                              hipStream_t stream) {
    const float* emb = (const float*)d_in[0];
    const float* th  = (const float*)d_in[1];
    float* out = (float*)d_out;
    char* ws = (char*)d_ws;

    unsigned short* e    = (unsigned short*)(ws);                 // 8 MB bf16 [N][D]
    float4*   th4        = (float4*)(ws + 8388608);               // 128 KB
    float*    srow       = (float*)(ws + 8519680);                // 32 KB
    unsigned* jminr      = (unsigned*)(ws + 8552448);             // 32 KB
    unsigned* negr       = (unsigned*)(ws + 8585216);             // 32 KB
    float*    pr         = (float*)(ws + 8617984);                // 32 KB
    float*    vf         = (float*)(ws + 8650752);                // 32 KB
    unsigned* d2mb       = (unsigned*)(ws + 8683520);             // 4 B

    knorm<<<N / 4, 256, 0, stream>>>(emb, e, th, th4, srow, jminr, negr, d2mb);
    kd2max<<<1024, 256, 0, stream>>>(th4, d2mb);
    kmain<<<2080, 256, 0, stream>>>(e, th4, d2mb, srow, jminr, negr);
    krow<<<N / 4, 256, 0, stream>>>(e, srow, jminr, negr, pr, vf);
    kfinal<<<1, 1024, 0, stream>>>(pr, vf, out);
}